// Round 12
// baseline (224.370 us; speedup 1.0000x reference)
//
#include <hip/hip_runtime.h>

typedef unsigned short u16;
typedef __attribute__((ext_vector_type(8))) short s8;   // 8 bf16 (4 VGPR) MFMA frag
typedef __attribute__((ext_vector_type(4))) float f4;   // 4 f32 acc frag

#define B_  8
#define C_  64
#define H_  128
#define W_  128
#define HW_ (H_*W_)
#define PITCH 72     // LDS shorts per pixel (144 B rows, 16B-aligned, uniform bank spread)
#define WSZ 36864    // elems of one transformed weight tensor [9][64][64]
#define NBLK 1024    // grid; exactly 4 blocks/CU x 256 CUs resident

// tile: 8 rows x 16 cols output, halo 10 x 18. Grid 1024 flat, 256 threads.
// XCD swizzle: b = L&7 -> xcd == batch image (verified r7: FETCH 126->36.8 MB).
// r11: hipLaunchCooperativeKernel gate refused (runtime occupancy model, likely
// 64KB-LDS-based) -> fallback ran. This round: plain launch + manual device-scope
// grid barrier. Residency is guaranteed by arithmetic (30720B LDS x4 = 122880 <=
// 163840; VGPR<=128 -> 4 waves/SIMD) and gated at runtime by hipFuncGetAttributes
// (numRegs<=128, no scratch) + CU count. Gate fail -> proven 3-kernel path (222us).

// f32 -> bf16 bits, round-to-nearest-even (finite only)
static __device__ __forceinline__ u16 f2bu(float f) {
    union { float f; unsigned u; } c; c.f = f;
    unsigned u = c.u;
    u += 0x7fffu + ((u >> 16) & 1u);
    return (u16)(u >> 16);
}
static __device__ __forceinline__ float bu2f(u16 u) {
    union { unsigned u; float f; } c; c.u = ((unsigned)u) << 16; return c.f;
}

// ---------- weight transform: 4x [o][c][3][3] f32 -> [cid][p][o][c] bf16 ----------
__global__ __launch_bounds__(256) void wt_all(
    const float* __restrict__ w0, const float* __restrict__ w1,
    const float* __restrict__ w2, const float* __restrict__ w3,
    u16* __restrict__ dst)
{
    int idx = blockIdx.x*256 + threadIdx.x;            // 0..36863
    int cid = blockIdx.y;
    const float* w = (cid == 0) ? w0 : (cid == 1) ? w1 : (cid == 2) ? w2 : w3;
    int p = idx >> 12, o = (idx >> 6) & 63, c = idx & 63;
    dst[(size_t)cid*WSZ + idx] = f2bu(w[((size_t)o*64 + c)*9 + p]);
}

// ---------- staging: bf16 NHWC -> LDS [pix][ch] (stage 2 inputs) ----------
static __device__ __forceinline__ void stage_tile(
    u16* __restrict__ s_t, const u16* __restrict__ src, int b, int th0, int tw0, int t)
{
    for (int i = t; i < 10*18*8; i += 256) {
        int pix = i >> 3, ch = i & 7;
        int rr = pix / 18, ww = pix - rr*18;
        int gr = th0 + rr - 1, gw = tw0 + ww - 1;
        uint4 v = {0u,0u,0u,0u};
        if ((unsigned)gr < (unsigned)H_ && (unsigned)gw < (unsigned)W_)
            v = *(const uint4*)(src + ((size_t)b*HW_ + gr*W_ + gw)*64 + ch*8);
        *(uint4*)(&s_t[pix*PITCH + ch*8]) = v;
    }
}

// ---------- staging: f32 NCHW -> LDS [pix][ch] bf16 (stage 1 inputs) ----------
// task i in [0,320): cp = i&31 (channel pair), rr = i>>5 (halo row 0..9).
static __device__ __forceinline__ void stage_tile_f32(
    u16* __restrict__ s_t, const float* __restrict__ src, int b, int th0, int tw0, int t)
{
    const bool lok = (tw0 != 0);         // wave-uniform edge flags
    const bool rok = (tw0 != W_ - 16);
    for (int i = t; i < 320; i += 256) {
        const int cp = i & 31, rr = i >> 5;
        const int gr = th0 + rr - 1;
        const int c0 = cp * 2;
        float v0[18], v1[18];
        if ((unsigned)gr < (unsigned)H_) {
            const float* a0 = src + ((size_t)b*C_ + c0)*HW_ + (size_t)gr*W_ + tw0;
            const float* a1 = a0 + HW_;
            v0[0]  = lok ? a0[-1] : 0.f;
            v1[0]  = lok ? a1[-1] : 0.f;
#pragma unroll
            for (int g = 0; g < 4; ++g) {
                *(f4*)(v0 + 1 + g*4) = *(const f4*)(a0 + g*4);   // 16B-aligned
                *(f4*)(v1 + 1 + g*4) = *(const f4*)(a1 + g*4);
            }
            v0[17] = rok ? a0[16] : 0.f;
            v1[17] = rok ? a1[16] : 0.f;
        } else {
#pragma unroll
            for (int j = 0; j < 18; ++j) { v0[j] = 0.f; v1[j] = 0.f; }
        }
#pragma unroll
        for (int j = 0; j < 18; ++j) {
            unsigned pk = (unsigned)f2bu(v0[j]) | ((unsigned)f2bu(v1[j]) << 16);
            *(unsigned*)(&s_t[(rr*18 + j)*PITCH + c0]) = pk;
        }
    }
}

// conv core: D = sum_p [kern_p ⊙] W_p[32och,64c] x X_p[64c,64px], f32 acc, bias init.
// wave (wvM,wvN): och half wvM, pixel rows wvN*4+nf; frag maps verified (rounds 1/4/5).
template<bool PAC>
static __device__ __forceinline__ void conv_core(
    const u16* __restrict__ s_t, const float* __restrict__ s_k,
    const u16* __restrict__ w, const float* __restrict__ bias,
    f4 acc[2][4], int wvM, int wvN, int ln, int quad)
{
#pragma unroll
    for (int mf = 0; mf < 2; ++mf) {
        f4 bv;
#pragma unroll
        for (int r = 0; r < 4; ++r) bv[r] = bias[wvM*32 + mf*16 + quad*4 + r];
#pragma unroll
        for (int nf = 0; nf < 4; ++nf) acc[mf][nf] = bv;
    }

#pragma unroll
    for (int p = 0; p < 9; ++p) {
        const int dr = p / 3, dc = p - dr*3;
        s8 a[2][2];
#pragma unroll
        for (int mf = 0; mf < 2; ++mf)
#pragma unroll
            for (int kc = 0; kc < 2; ++kc)
                a[mf][kc] = *(const s8*)(w + (((size_t)p*64 + wvM*32 + mf*16 + ln)*64 + kc*32 + quad*8));
        s8 bfr[4][2];
#pragma unroll
        for (int nf = 0; nf < 4; ++nf) {
            const u16* base = &s_t[((wvN*4 + nf + dr)*18 + ln + dc)*PITCH];
#pragma unroll
            for (int kc = 0; kc < 2; ++kc)
                bfr[nf][kc] = *(const s8*)(base + kc*32 + quad*8);
        }
        if (PAC) {
            float kv[4];
#pragma unroll
            for (int nf = 0; nf < 4; ++nf)
                kv[nf] = s_k[p*128 + (wvN*4 + nf)*16 + ln];
#pragma unroll
            for (int mf = 0; mf < 2; ++mf)
#pragma unroll
                for (int nf = 0; nf < 4; ++nf) {
                    f4 d = {0.f, 0.f, 0.f, 0.f};
                    d = __builtin_amdgcn_mfma_f32_16x16x32_bf16(a[mf][0], bfr[nf][0], d, 0, 0, 0);
                    d = __builtin_amdgcn_mfma_f32_16x16x32_bf16(a[mf][1], bfr[nf][1], d, 0, 0, 0);
                    acc[mf][nf] += kv[nf] * d;
                }
        } else {
#pragma unroll
            for (int mf = 0; mf < 2; ++mf)
#pragma unroll
                for (int nf = 0; nf < 4; ++nf) {
                    acc[mf][nf] = __builtin_amdgcn_mfma_f32_16x16x32_bf16(a[mf][0], bfr[nf][0], acc[mf][nf], 0, 0, 0);
                    acc[mf][nf] = __builtin_amdgcn_mfma_f32_16x16x32_bf16(a[mf][1], bfr[nf][1], acc[mf][nf], 0, 0, 0);
                }
        }
    }
}

// epilogue: bf16 NHWC with relu (stage 1)
static __device__ __forceinline__ void store_t(
    u16* __restrict__ out, f4 acc[2][4], int b, int th0, int tw0,
    int wvM, int wvN, int ln, int quad)
{
#pragma unroll
    for (int mf = 0; mf < 2; ++mf)
#pragma unroll
        for (int nf = 0; nf < 4; ++nf) {
            f4 v = acc[mf][nf];
            ushort4 o;
            o.x = f2bu(fmaxf(v[0], 0.f)); o.y = f2bu(fmaxf(v[1], 0.f));
            o.z = f2bu(fmaxf(v[2], 0.f)); o.w = f2bu(fmaxf(v[3], 0.f));
            size_t pix = (size_t)b*HW_ + (th0 + wvN*4 + nf)*W_ + tw0 + ln;
            *(ushort4*)(out + pix*64 + wvM*32 + mf*16 + quad*4) = o;
        }
}

// epilogue: f32 NCHW out + residual read from f32 NCHW (stage 2; exact, coalesced)
static __device__ __forceinline__ void store_f(
    float* __restrict__ out, const float* __restrict__ resid,
    f4 acc[2][4], int b, int th0, int tw0, int wvM, int wvN, int ln, int quad)
{
#pragma unroll
    for (int mf = 0; mf < 2; ++mf)
#pragma unroll
        for (int nf = 0; nf < 4; ++nf) {
#pragma unroll
            for (int r = 0; r < 4; ++r) {
                int och = wvM*32 + mf*16 + quad*4 + r;
                size_t idx = ((size_t)b*C_ + och)*HW_ + (th0 + wvN*4 + nf)*W_ + tw0 + ln;
                out[idx] = acc[mf][nf][r] + resid[idx];
            }
        }
}

// ---------- one fused stage body (r7 structure, verified) ----------
template<bool STAGE1>
static __device__ __forceinline__ void phase_body(
    const float* __restrict__ inA_f, const float* __restrict__ inB_f,
    const u16* __restrict__ inA_t, const u16* __restrict__ inB_t,
    const u16* __restrict__ wA, const u16* __restrict__ wB,
    const float* __restrict__ biasA, const float* __restrict__ biasB,
    const float* __restrict__ residA_f, const float* __restrict__ residB_f,
    u16* __restrict__ outA_t, u16* __restrict__ outB_t,
    float* __restrict__ outA_f, float* __restrict__ outB_f,
    u16* __restrict__ s_t, float* __restrict__ s_k)
{
    const int t    = threadIdx.x;
    const int L    = blockIdx.x;         // 0..1023; xcd = L&7 = batch image
    const int b    = L & 7;
    const int tw0  = ((L >> 3) & 7) * 16;
    const int th0  = (L >> 6) * 8;
    const int wv   = t >> 6;
    const int wvM  = wv >> 1;            // och half (0..1)
    const int wvN  = wv & 1;             // pixel-row half (0..1)
    const int lane = t & 63;
    const int ln   = lane & 15;
    const int quad = lane >> 4;

    // ---- phase 1: stage guide/inA tile ----
    if (STAGE1) stage_tile_f32(s_t, inA_f, b, th0, tw0, t);
    else        stage_tile    (s_t, inA_t, b, th0, tw0, t);
    __syncthreads();

    // ---- phase 2a: gaussian kernel from inA tile -> s_k ----
    {
        const int px   = t & 127;
        const int half = t >> 7;
        const int p0   = half ? 5 : 0;
        const int np   = half ? 4 : 5;
        const int py   = px >> 4, pxc = px & 15;
        float d2[5];
#pragma unroll
        for (int k = 0; k < 5; ++k) d2[k] = 0.f;
        const u16* cb = &s_t[((py+1)*18 + (pxc+1))*PITCH];
#pragma unroll 1
        for (int co = 0; co < 8; ++co) {
            s8 c8 = *(const s8*)(cb + co*8);
            float cf[8];
#pragma unroll
            for (int j = 0; j < 8; ++j) cf[j] = bu2f((u16)c8[j]);
#pragma unroll
            for (int k = 0; k < 5; ++k) {
                if (k < np) {
                    int p = p0 + k;
                    int dr = p / 3, dc = p - dr*3;
                    s8 n8 = *(const s8*)(&s_t[((py + dr)*18 + pxc + dc)*PITCH + co*8]);
#pragma unroll
                    for (int j = 0; j < 8; ++j) {
                        float d = bu2f((u16)n8[j]) - cf[j];
                        d2[k] += d * d;
                    }
                }
            }
        }
#pragma unroll
        for (int k = 0; k < 5; ++k)
            if (k < np) s_k[(p0+k)*128 + px] = __expf(-0.5f * d2[k]);
    }

    // ---- phase 2b: convA (plain) on inA tile ----
    {
        f4 acc[2][4];
        conv_core<false>(s_t, nullptr, wA, biasA, acc, wvM, wvN, ln, quad);
        if (STAGE1) store_t(outA_t, acc, b, th0, tw0, wvM, wvN, ln, quad);
        else        store_f(outA_f, residA_f, acc, b, th0, tw0, wvM, wvN, ln, quad);
    }

    // ---- phase 3: restage with inB tile (also orders s_k writes before reads) ----
    __syncthreads();
    if (STAGE1) stage_tile_f32(s_t, inB_f, b, th0, tw0, t);
    else        stage_tile    (s_t, inB_t, b, th0, tw0, t);
    __syncthreads();

    // ---- phase 4: convB (PAC with s_k) on inB tile ----
    {
        f4 acc[2][4];
        conv_core<true>(s_t, s_k, wB, biasB, acc, wvM, wvN, ln, quad);
        if (STAGE1) store_t(outB_t, acc, b, th0, tw0, wvM, wvN, ln, quad);
        else        store_f(outB_f, residB_f, acc, b, th0, tw0, wvM, wvN, ln, quad);
    }
}

// ---------- fallback path: r7/r11's standalone stage kernel ----------
template<bool STAGE1>
__global__ __launch_bounds__(256, 2) void fused_stage(
    const float* __restrict__ inA_f, const float* __restrict__ inB_f,
    const u16* __restrict__ inA_t, const u16* __restrict__ inB_t,
    const u16* __restrict__ wA, const u16* __restrict__ wB,
    const float* __restrict__ biasA, const float* __restrict__ biasB,
    const float* __restrict__ residA_f, const float* __restrict__ residB_f,
    u16* __restrict__ outA_t, u16* __restrict__ outB_t,
    float* __restrict__ outA_f, float* __restrict__ outB_f)
{
    __shared__ u16   s_t[10*18*PITCH];   // 25920 B
    __shared__ float s_k[9*128];         //  4608 B  (30528 B total)
    phase_body<STAGE1>(inA_f, inB_f, inA_t, inB_t, wA, wB, biasA, biasB,
                       residA_f, residB_f, outA_t, outB_t, outA_f, outB_f, s_t, s_k);
}

// ---------- manual device-scope grid barrier ----------
// Standard pattern: all threads fence, block-sync, thread0 arrives with agent-scope
// acq_rel atomic; last arriver resets counter and bumps generation (release);
// waiters spin on generation (acquire). Safe iff ALL gridDim blocks are resident,
// which launch config + the host gate guarantee.
static __device__ __forceinline__ void grid_barrier(unsigned* bar)
{
    __threadfence();                      // publish this thread's prior writes
    __syncthreads();
    if (threadIdx.x == 0) {
        unsigned* counter = bar;          // cache line 0
        unsigned* gen     = bar + 32;     // cache line 1 (+128 B)
        unsigned g = __hip_atomic_load(gen, __ATOMIC_RELAXED, __HIP_MEMORY_SCOPE_AGENT);
        unsigned a = __hip_atomic_fetch_add(counter, 1u, __ATOMIC_ACQ_REL, __HIP_MEMORY_SCOPE_AGENT);
        if (a == NBLK - 1u) {
            __hip_atomic_store(counter, 0u, __ATOMIC_RELAXED, __HIP_MEMORY_SCOPE_AGENT);
            __hip_atomic_store(gen, g + 1u, __ATOMIC_RELEASE, __HIP_MEMORY_SCOPE_AGENT);
        } else {
            while (__hip_atomic_load(gen, __ATOMIC_ACQUIRE, __HIP_MEMORY_SCOPE_AGENT) == g)
                __builtin_amdgcn_s_sleep(2);
        }
        __threadfence();                  // acquire side: invalidate stale caches
    }
    __syncthreads();
}

// ---------- the single merged kernel: wt -> bar -> stage1 -> bar -> stage2 ----------
__global__ __launch_bounds__(256, 2) void fused_all(
    const float* __restrict__ x, const float* __restrict__ edge,
    const float* __restrict__ w_pac1, const float* __restrict__ b_pac1,
    const float* __restrict__ w_pac2, const float* __restrict__ b_pac2,
    const float* __restrict__ w_e1,  const float* __restrict__ b_e1,
    const float* __restrict__ w_e2,  const float* __restrict__ b_e2,
    u16* __restrict__ res_edge1_t, u16* __restrict__ res_sr1_t,
    u16* __restrict__ w_t, float* __restrict__ out_sr, float* __restrict__ out_edge,
    unsigned* __restrict__ bar)
{
    __shared__ u16   s_t[10*18*PITCH];   // 25920 B
    __shared__ float s_k[9*128];         //  4608 B  (30528 B total)

    // ---- prologue: weight transform, 1 elem/thread (147456 < 262144 threads) ----
    {
        int gid = blockIdx.x*256 + threadIdx.x;
        if (gid < 4*WSZ) {
            int cid = gid / WSZ;                        // 0=e1, 1=pac1, 2=e2, 3=pac2
            int idx = gid - cid*WSZ;
            const float* w = (cid == 0) ? w_e1 : (cid == 1) ? w_pac1
                           : (cid == 2) ? w_e2 : w_pac2;
            int p = idx >> 12, o = (idx >> 6) & 63, c = idx & 63;
            w_t[(size_t)cid*WSZ + idx] = f2bu(w[((size_t)o*64 + c)*9 + p]);
        }
    }
    grid_barrier(bar);

    // ---- stage 1: gauss(edge) + conv_e1(edge) + pac1(x) -> bf16 NHWC res tiles ----
    phase_body<true>(edge, x, nullptr, nullptr,
                     w_t + 0*WSZ, w_t + 1*WSZ, b_e1, b_pac1,
                     nullptr, nullptr, res_edge1_t, res_sr1_t, nullptr, nullptr,
                     s_t, s_k);
    grid_barrier(bar);

    // ---- stage 2: gauss(res_edge1) + conv_e2+edge_resid + pac2+x_resid -> f32 NCHW ----
    phase_body<false>(nullptr, nullptr, res_edge1_t, res_sr1_t,
                      w_t + 2*WSZ, w_t + 3*WSZ, b_e2, b_pac2,
                      edge, x, nullptr, nullptr, out_edge, out_sr,
                      s_t, s_k);
}

extern "C" void kernel_launch(void* const* d_in, const int* in_sizes, int n_in,
                              void* d_out, int out_size, void* d_ws, size_t ws_size,
                              hipStream_t stream)
{
    const float* x      = (const float*)d_in[0];
    const float* edge   = (const float*)d_in[1];
    const float* w_pac1 = (const float*)d_in[2];
    const float* b_pac1 = (const float*)d_in[3];
    const float* w_pac2 = (const float*)d_in[4];
    const float* b_pac2 = (const float*)d_in[5];
    const float* w_e1   = (const float*)d_in[6];
    const float* b_e1   = (const float*)d_in[7];
    const float* w_e2   = (const float*)d_in[8];
    const float* b_e2   = (const float*)d_in[9];

    float* out_sr   = (float*)d_out;
    float* out_edge = out_sr + (size_t)B_*C_*HW_;

    const size_t NT = (size_t)B_*HW_*64;
    u16* res_edge1_t = (u16*)d_ws;
    u16* res_sr1_t   = res_edge1_t + NT;
    u16* w_t         = res_sr1_t + NT;    // [4][9][64][64]: 0=e1, 1=pac1, 2=e2, 3=pac2
    unsigned* bar    = (unsigned*)(w_t + 4*WSZ);   // 2 cache lines of barrier state

    // Gate on compiler facts, not the runtime occupancy model (which refused r11's
    // cooperative launch): need VGPR<=128 (4 waves/SIMD -> 4 blocks/CU with 30.5KB
    // LDS) and zero scratch, on a full 256-CU part. Then all 1024 blocks are
    // co-resident and the manual grid barrier is safe.
    static int mode = -1;
    if (mode < 0) {
        hipFuncAttributes attr{};
        hipError_t e = hipFuncGetAttributes(&attr, reinterpret_cast<const void*>(&fused_all));
        int cus = 0;
        {
            hipDeviceProp_t prop{};
            int dev = 0;
            if (hipGetDevice(&dev) == hipSuccess &&
                hipGetDeviceProperties(&prop, dev) == hipSuccess)
                cus = prop.multiProcessorCount;
        }
        mode = (e == hipSuccess && attr.numRegs > 0 && attr.numRegs <= 128 &&
                attr.localSizeBytes == 0 && attr.sharedSizeBytes <= 40960 &&
                cus >= 256) ? 1 : 0;
    }

    if (mode == 1) {
        hipMemsetAsync(bar, 0, 256, stream);   // zero barrier state (captured per replay)
        fused_all<<<dim3(NBLK), dim3(256), 0, stream>>>(
            x, edge, w_pac1, b_pac1, w_pac2, b_pac2,
            w_e1, b_e1, w_e2, b_e2,
            res_edge1_t, res_sr1_t, w_t, out_sr, out_edge, bar);
    } else {
        // fallback: proven r11 3-kernel path (222 us)
        wt_all<<<dim3(144, 4), dim3(256), 0, stream>>>(w_e1, w_pac1, w_e2, w_pac2, w_t);
        fused_stage<true ><<<dim3(1024), dim3(256), 0, stream>>>(
            edge, x, nullptr, nullptr,
            w_t + 0*WSZ, w_t + 1*WSZ, b_e1, b_pac1,
            nullptr, nullptr, res_edge1_t, res_sr1_t, nullptr, nullptr);
        fused_stage<false><<<dim3(1024), dim3(256), 0, stream>>>(
            nullptr, nullptr, res_edge1_t, res_sr1_t,
            w_t + 2*WSZ, w_t + 3*WSZ, b_e2, b_pac2,
            edge, x, nullptr, nullptr, out_edge, out_sr);
    }
}